// Round 1
// baseline (67.069 us; speedup 1.0000x reference)
//
#include <hip/hip_runtime.h>
#include <math.h>

#define HH 256
#define WW 256
#define CC 3
#define HW (HH*WW)
#define PW 264              // padded width/height (pad=4 each side)
#define PHW (PW*PW)         // 69696 floats per padded channel plane
#define NPAD (4*CC*PHW)     // total padded elements = 836352 (exactly 3267*256)

// Map r^2 = dx^2+dy^2 (dx,dy in -4..4) -> compact weight index 0..14.
// Achievable r^2 values: 0,1,2,4,5,8,9,10,13,16,17,18,20,25,32 (15 values).
__device__ constexpr int CMAP[33] = {
     0,  1,  2, -1,  3,  4, -1, -1,
     5,  6,  7, -1, -1,  8, -1, -1,
     9, 10, 11, -1, 12, -1, -1, -1,
    -1, 13, -1, -1, -1, -1, -1, -1,
    14
};

// ---------------- Kernel A: reflect-pad x into workspace ----------------
// xp[b][c][264][264], xp[r][col] = x[reflect(r-4)][reflect(col-4)]
__global__ __launch_bounds__(256) void pad_kernel(
    const float* __restrict__ x, float* __restrict__ xp)
{
    const int idx = blockIdx.x * 256 + threadIdx.x;   // 0 .. NPAD-1 (exact grid)
    const int col  = idx % PW;
    const int rest = idx / PW;
    const int row  = rest % PW;
    const int bc   = rest / PW;

    int sx = col - 4;
    sx = (sx < 0) ? -sx : sx;
    sx = (sx > WW-1) ? (2*(WW-1) - sx) : sx;
    int sy = row - 4;
    sy = (sy < 0) ? -sy : sy;
    sy = (sy > HH-1) ? (2*(HH-1) - sy) : sy;

    xp[idx] = x[bc * HW + sy * WW + sx];
}

// ---------------- Kernel B: 4 px/thread, float4 loads from padded ----------------
__global__ __launch_bounds__(256) void adaptive_log4(
    const float* __restrict__ xp, const float* __restrict__ foa,
    float* __restrict__ out)
{
    const int gid = blockIdx.x * 256 + threadIdx.x;  // 0..16383 per image
    const int b   = blockIdx.y;
    const int p0  = gid << 2;                        // first of 4 pixels
    const int py  = p0 >> 8;                         // wave-uniform
    const int px  = p0 & (WW - 1);                   // multiple of 4

    // ---- per-sub-pixel weights (15 distinct r^2 values each) ----
    const float fx = foa[2*b + 0];
    const float fy = foa[2*b + 1];
    const float dyc = (float)py - fy;
    const float inv_diag = 1.0f / 362.03867196751236f;  // 1/sqrt(256^2+256^2)

    float w[4][15];
    constexpr int r2v[15] = {0,1,2,4,5,8,9,10,13,16,17,18,20,25,32};
    #pragma unroll
    for (int j = 0; j < 4; ++j) {
        const float ddx  = (float)(px + j) - fx;
        const float dist = sqrtf(ddx*ddx + dyc*dyc);
        const float dn    = dist * inv_diag;
        const float sigma = 0.5f + 9.5f * dn;            // (1-dn)*0.5 + dn*10
        const float s2    = sigma * sigma;
        const float inv2s2 = 0.5f / s2;
        const float common = (-1.0f / (float)M_PI) / (s2 * s2) * sqrtf(sigma) * dist;
        #pragma unroll
        for (int i = 0; i < 15; ++i) {
            const float t = (float)r2v[i] * inv2s2;
            w[j][i] = common * (1.0f - t) * __expf(-t);
        }
    }

    // padded base: output row py needs padded rows py..py+8, padded cols px..px+11
    const float* base = xp + (size_t)(b * CC) * PHW + (size_t)py * PW + px;

    #pragma unroll
    for (int c = 0; c < CC; ++c) {
        float a0 = 0.f, a1 = 0.f, a2 = 0.f, a3 = 0.f;
        const float* cb = base + (size_t)c * PHW;
        #pragma unroll
        for (int a = 0; a < 9; ++a) {
            const float4 q0 = *reinterpret_cast<const float4*>(cb + a*PW);
            const float4 q1 = *reinterpret_cast<const float4*>(cb + a*PW + 4);
            const float4 q2 = *reinterpret_cast<const float4*>(cb + a*PW + 8);
            const float q[12] = {q0.x,q0.y,q0.z,q0.w,
                                 q1.x,q1.y,q1.z,q1.w,
                                 q2.x,q2.y,q2.z,q2.w};
            const int dy = a - 4;
            #pragma unroll
            for (int bb = 0; bb < 9; ++bb) {
                const int dx = bb - 4;
                const int wi = CMAP[dy*dy + dx*dx];      // compile-time constant
                a0 += w[0][wi] * q[bb + 0];
                a1 += w[1][wi] * q[bb + 1];
                a2 += w[2][wi] * q[bb + 2];
                a3 += w[3][wi] * q[bb + 3];
            }
        }
        float* ob = out + (size_t)(b * CC + c) * HW + p0;
        *reinterpret_cast<float4*>(ob) = make_float4(a0, a1, a2, a3);
    }
}

// ---------------- Fallback (previous proven kernel) if workspace too small ----------------
__global__ __launch_bounds__(256) void adaptive_log_kernel_fb(
    const float* __restrict__ x, const float* __restrict__ foa,
    float* __restrict__ out)
{
    const int p  = blockIdx.x * 256 + threadIdx.x;
    const int b  = blockIdx.y;
    const int py = p >> 8;
    const int px = p & (WW - 1);

    const float fx = foa[2*b + 0];
    const float fy = foa[2*b + 1];
    const float ddx = (float)px - fx;
    const float ddy = (float)py - fy;
    const float dist = sqrtf(ddx*ddx + ddy*ddy);
    const float dn = dist * (1.0f / 362.03867196751236f);
    const float sigma = 0.5f + 9.5f * dn;
    const float s2 = sigma * sigma;
    const float inv2s2 = 0.5f / s2;
    const float factor = -1.0f / ((float)M_PI * s2 * s2);
    const float common = factor * sqrtf(sigma) * dist;

    float w[33];
    const int r2v[16] = {0,1,2,4,5,8,9,10,13,16,17,18,20,25,26,32};
    #pragma unroll
    for (int i = 0; i < 16; ++i) {
        const float t = (float)r2v[i] * inv2s2;
        w[r2v[i]] = common * (1.0f - t) * __expf(-t);
    }

    int xi[9], yi[9];
    #pragma unroll
    for (int i = 0; i < 9; ++i) {
        int xx = px + i - 4;
        xx = (xx < 0) ? -xx : xx;
        xx = (xx > WW-1) ? (2*(WW-1) - xx) : xx;
        xi[i] = xx;
        int yy = py + i - 4;
        yy = (yy < 0) ? -yy : yy;
        yy = (yy > HH-1) ? (2*(HH-1) - yy) : yy;
        yi[i] = yy * WW;
    }

    const float* xb = x + (size_t)b * (CC*HW);
    float a0 = 0.f, a1 = 0.f, a2 = 0.f;
    #pragma unroll
    for (int a = 0; a < 9; ++a) {
        const int dy = a - 4;
        #pragma unroll
        for (int bb = 0; bb < 9; ++bb) {
            const int dx = bb - 4;
            const float wv = w[dy*dy + dx*dx];
            const int off = yi[a] + xi[bb];
            a0 += wv * xb[off];
            a1 += wv * xb[off + HW];
            a2 += wv * xb[off + 2*HW];
        }
    }

    float* ob = out + (size_t)b * (CC*HW);
    ob[p]          = a0;
    ob[p + HW]     = a1;
    ob[p + 2*HW]   = a2;
}

extern "C" void kernel_launch(void* const* d_in, const int* in_sizes, int n_in,
                              void* d_out, int out_size, void* d_ws, size_t ws_size,
                              hipStream_t stream) {
    const float* x   = (const float*)d_in[0];   // [4,3,256,256] f32
    const float* foa = (const float*)d_in[1];   // [4,2] f32
    float* out = (float*)d_out;                 // [4,3,256,256] f32

    if (d_ws != nullptr && ws_size >= (size_t)NPAD * sizeof(float)) {
        float* xp = (float*)d_ws;
        pad_kernel<<<dim3(NPAD / 256), dim3(256), 0, stream>>>(x, xp);
        adaptive_log4<<<dim3((HW/4) / 256, 4), dim3(256), 0, stream>>>(xp, foa, out);
    } else {
        adaptive_log_kernel_fb<<<dim3(HW / 256, 4), dim3(256), 0, stream>>>(x, foa, out);
    }
}

// Round 2
// 66.542 us; speedup vs baseline: 1.0079x; 1.0079x over previous
//
#include <hip/hip_runtime.h>
#include <math.h>

#define HH 256
#define WW 256
#define CC 3
#define HW (HH*WW)
#define PW 264              // padded width/height (pad=4 each side)
#define PHW (PW*PW)         // 69696 floats per padded channel plane
#define NPAD (4*CC*PHW)     // total padded elements = 836352 (exactly 3267*256)

// Map r^2 = dx^2+dy^2 (dx,dy in -4..4) -> compact weight index 0..14.
// Achievable r^2 values: 0,1,2,4,5,8,9,10,13,16,17,18,20,25,32 (15 values).
__device__ constexpr int CMAP[33] = {
     0,  1,  2, -1,  3,  4, -1, -1,
     5,  6,  7, -1, -1,  8, -1, -1,
     9, 10, 11, -1, 12, -1, -1, -1,
    -1, 13, -1, -1, -1, -1, -1, -1,
    14
};

// ---------------- Kernel A: reflect-pad x into workspace ----------------
// xp[b][c][264][264], xp[r][col] = x[reflect(r-4)][reflect(col-4)]
__global__ __launch_bounds__(256) void pad_kernel(
    const float* __restrict__ x, float* __restrict__ xp)
{
    const int idx = blockIdx.x * 256 + threadIdx.x;   // 0 .. NPAD-1 (exact grid)
    const int col  = idx % PW;
    const int rest = idx / PW;
    const int row  = rest % PW;
    const int bc   = rest / PW;

    int sx = col - 4;
    sx = (sx < 0) ? -sx : sx;
    sx = (sx > WW-1) ? (2*(WW-1) - sx) : sx;
    int sy = row - 4;
    sy = (sy < 0) ? -sy : sy;
    sy = (sy > HH-1) ? (2*(HH-1) - sy) : sy;

    xp[idx] = x[bc * HW + sy * WW + sx];
}

// ---------------- Kernel B: 4 px/thread, one channel per block ----------------
// grid = (64, 12): blockIdx.y = b*? -> b = y&3, c = y>>2. 768 blocks = 3 blocks/CU.
__global__ __launch_bounds__(256) void adaptive_log4c(
    const float* __restrict__ xp, const float* __restrict__ foa,
    float* __restrict__ out)
{
    const int gid = blockIdx.x * 256 + threadIdx.x;  // 0..16383 per image
    const int b   = blockIdx.y & 3;                  // batch
    const int c   = blockIdx.y >> 2;                 // channel 0..2
    const int p0  = gid << 2;                        // first of 4 pixels
    const int py  = p0 >> 8;                         // wave-uniform row
    const int px  = p0 & (WW - 1);                   // multiple of 4

    // ---- per-sub-pixel weights (15 distinct r^2), 1 exp + power chain ----
    const float fx = foa[2*b + 0];
    const float fy = foa[2*b + 1];
    const float dyc = (float)py - fy;
    const float inv_diag = 1.0f / 362.03867196751236f;  // 1/sqrt(256^2+256^2)

    float w[4][15];
    constexpr int r2v[15] = {0,1,2,4,5,8,9,10,13,16,17,18,20,25,32};
    #pragma unroll
    for (int j = 0; j < 4; ++j) {
        const float ddx  = (float)(px + j) - fx;
        const float dist = sqrtf(ddx*ddx + dyc*dyc);
        const float dn    = dist * inv_diag;
        const float sigma = 0.5f + 9.5f * dn;            // (1-dn)*0.5 + dn*10
        const float s2    = sigma * sigma;
        const float inv2s2 = 0.5f / s2;
        const float common = (-1.0f / (float)M_PI) / (s2 * s2) * sqrtf(sigma) * dist;

        // u^(r^2) power chain: exp(-r2 * inv2s2) = u1^r2
        const float u1  = __expf(-inv2s2);
        const float u2  = u1 * u1;
        const float u4  = u2 * u2;
        const float u8  = u4 * u4;
        const float u16 = u8 * u8;
        const float u32 = u16 * u16;
        const float u5  = u4 * u1;
        const float u9  = u8 * u1;
        const float u10 = u8 * u2;
        const float u13 = u9 * u4;
        const float u17 = u16 * u1;
        const float u18 = u16 * u2;
        const float u20 = u16 * u4;
        const float u25 = u16 * u9;
        const float uu[15] = {1.0f,u1,u2,u4,u5,u8,u9,u10,u13,u16,u17,u18,u20,u25,u32};

        #pragma unroll
        for (int i = 0; i < 15; ++i) {
            w[j][i] = common * (1.0f - (float)r2v[i] * inv2s2) * uu[i];
        }
    }

    // padded plane for (b,c); window rows py..py+8, cols px..px+11 (all aligned)
    const float* cb = xp + (size_t)(b * CC + c) * PHW + (size_t)py * PW + px;

    float a0 = 0.f, a1 = 0.f, a2 = 0.f, a3 = 0.f;
    #pragma unroll
    for (int a = 0; a < 9; ++a) {
        const float4 q0 = *reinterpret_cast<const float4*>(cb + a*PW);
        const float4 q1 = *reinterpret_cast<const float4*>(cb + a*PW + 4);
        const float4 q2 = *reinterpret_cast<const float4*>(cb + a*PW + 8);
        const float q[12] = {q0.x,q0.y,q0.z,q0.w,
                             q1.x,q1.y,q1.z,q1.w,
                             q2.x,q2.y,q2.z,q2.w};
        const int dy = a - 4;
        #pragma unroll
        for (int bb = 0; bb < 9; ++bb) {
            const int dx = bb - 4;
            const int wi = CMAP[dy*dy + dx*dx];      // compile-time constant
            a0 += w[0][wi] * q[bb + 0];
            a1 += w[1][wi] * q[bb + 1];
            a2 += w[2][wi] * q[bb + 2];
            a3 += w[3][wi] * q[bb + 3];
        }
    }
    float* ob = out + (size_t)(b * CC + c) * HW + p0;
    *reinterpret_cast<float4*>(ob) = make_float4(a0, a1, a2, a3);
}

// ---------------- Fallback (round-0 proven kernel) if workspace too small ----------------
__global__ __launch_bounds__(256) void adaptive_log_kernel_fb(
    const float* __restrict__ x, const float* __restrict__ foa,
    float* __restrict__ out)
{
    const int p  = blockIdx.x * 256 + threadIdx.x;
    const int b  = blockIdx.y;
    const int py = p >> 8;
    const int px = p & (WW - 1);

    const float fx = foa[2*b + 0];
    const float fy = foa[2*b + 1];
    const float ddx = (float)px - fx;
    const float ddy = (float)py - fy;
    const float dist = sqrtf(ddx*ddx + ddy*ddy);
    const float dn = dist * (1.0f / 362.03867196751236f);
    const float sigma = 0.5f + 9.5f * dn;
    const float s2 = sigma * sigma;
    const float inv2s2 = 0.5f / s2;
    const float factor = -1.0f / ((float)M_PI * s2 * s2);
    const float common = factor * sqrtf(sigma) * dist;

    float w[33];
    const int r2v[16] = {0,1,2,4,5,8,9,10,13,16,17,18,20,25,26,32};
    #pragma unroll
    for (int i = 0; i < 16; ++i) {
        const float t = (float)r2v[i] * inv2s2;
        w[r2v[i]] = common * (1.0f - t) * __expf(-t);
    }

    int xi[9], yi[9];
    #pragma unroll
    for (int i = 0; i < 9; ++i) {
        int xx = px + i - 4;
        xx = (xx < 0) ? -xx : xx;
        xx = (xx > WW-1) ? (2*(WW-1) - xx) : xx;
        xi[i] = xx;
        int yy = py + i - 4;
        yy = (yy < 0) ? -yy : yy;
        yy = (yy > HH-1) ? (2*(HH-1) - yy) : yy;
        yi[i] = yy * WW;
    }

    const float* xb = x + (size_t)b * (CC*HW);
    float a0 = 0.f, a1 = 0.f, a2 = 0.f;
    #pragma unroll
    for (int a = 0; a < 9; ++a) {
        const int dy = a - 4;
        #pragma unroll
        for (int bb = 0; bb < 9; ++bb) {
            const int dx = bb - 4;
            const float wv = w[dy*dy + dx*dx];
            const int off = yi[a] + xi[bb];
            a0 += wv * xb[off];
            a1 += wv * xb[off + HW];
            a2 += wv * xb[off + 2*HW];
        }
    }

    float* ob = out + (size_t)b * (CC*HW);
    ob[p]          = a0;
    ob[p + HW]     = a1;
    ob[p + 2*HW]   = a2;
}

extern "C" void kernel_launch(void* const* d_in, const int* in_sizes, int n_in,
                              void* d_out, int out_size, void* d_ws, size_t ws_size,
                              hipStream_t stream) {
    const float* x   = (const float*)d_in[0];   // [4,3,256,256] f32
    const float* foa = (const float*)d_in[1];   // [4,2] f32
    float* out = (float*)d_out;                 // [4,3,256,256] f32

    if (d_ws != nullptr && ws_size >= (size_t)NPAD * sizeof(float)) {
        float* xp = (float*)d_ws;
        pad_kernel<<<dim3(NPAD / 256), dim3(256), 0, stream>>>(x, xp);
        adaptive_log4c<<<dim3((HW/4) / 256, 4 * CC), dim3(256), 0, stream>>>(xp, foa, out);
    } else {
        adaptive_log_kernel_fb<<<dim3(HW / 256, 4), dim3(256), 0, stream>>>(x, foa, out);
    }
}

// Round 3
// 66.493 us; speedup vs baseline: 1.0087x; 1.0007x over previous
//
#include <hip/hip_runtime.h>
#include <math.h>

#define HH 256
#define WW 256
#define CC 3
#define HW (HH*WW)

// Map r^2 = dx^2+dy^2 (dx,dy in -4..4) -> compact weight index 0..14.
// Achievable r^2 values: 0,1,2,4,5,8,9,10,13,16,17,18,20,25,32 (15 values).
__device__ constexpr int CMAP[33] = {
     0,  1,  2, -1,  3,  4, -1, -1,
     5,  6,  7, -1, -1,  8, -1, -1,
     9, 10, 11, -1, 12, -1, -1, -1,
    -1, 13, -1, -1, -1, -1, -1, -1,
    14
};

// Single fused kernel: 4 px/thread, one (batch,channel) plane per blockIdx.y.
// grid = (64, 12) = 768 blocks = 3 blocks/CU = 3 waves/SIMD.
// Columns: aligned float4 loads at clamped base; the 2 edge lanes per wave
// (px0==0 / px0==252) fix up via compile-time register permutation (reflect).
// Rows: reflected offsets (py is wave-uniform).
__global__ __launch_bounds__(256) void adaptive_log_fused(
    const float* __restrict__ x, const float* __restrict__ foa,
    float* __restrict__ out)
{
    const int gid = blockIdx.x * 256 + threadIdx.x;  // 0..16383 per plane
    const int b   = blockIdx.y & 3;                  // batch
    const int c   = blockIdx.y >> 2;                 // channel 0..2
    const int p0  = gid << 2;                        // first of 4 pixels
    const int py  = p0 >> 8;                         // wave-uniform row
    const int px0 = p0 & (WW - 1);                   // multiple of 4

    // ---- per-sub-pixel weights (15 distinct r^2), 1 exp + power chain ----
    const float fx = foa[2*b + 0];
    const float fy = foa[2*b + 1];
    const float dyc = (float)py - fy;
    const float inv_diag = 1.0f / 362.03867196751236f;  // 1/sqrt(256^2+256^2)

    float w[4][15];
    constexpr int r2v[15] = {0,1,2,4,5,8,9,10,13,16,17,18,20,25,32};
    #pragma unroll
    for (int j = 0; j < 4; ++j) {
        const float ddx  = (float)(px0 + j) - fx;
        const float dist = sqrtf(ddx*ddx + dyc*dyc);
        const float dn    = dist * inv_diag;
        const float sigma = 0.5f + 9.5f * dn;            // (1-dn)*0.5 + dn*10
        const float s2    = sigma * sigma;
        const float inv2s2 = 0.5f / s2;
        const float common = (-1.0f / (float)M_PI) / (s2 * s2) * sqrtf(sigma) * dist;

        // exp(-r2*inv2s2) = u1^r2 via power chain (1 transcendental)
        const float u1  = __expf(-inv2s2);
        const float u2  = u1 * u1;
        const float u4  = u2 * u2;
        const float u8  = u4 * u4;
        const float u16 = u8 * u8;
        const float u32 = u16 * u16;
        const float u5  = u4 * u1;
        const float u9  = u8 * u1;
        const float u10 = u8 * u2;
        const float u13 = u9 * u4;
        const float u17 = u16 * u1;
        const float u18 = u16 * u2;
        const float u20 = u16 * u4;
        const float u25 = u16 * u9;
        const float uu[15] = {1.0f,u1,u2,u4,u5,u8,u9,u10,u13,u16,u17,u18,u20,u25,u32};

        #pragma unroll
        for (int i = 0; i < 15; ++i) {
            w[j][i] = common * (1.0f - (float)r2v[i] * inv2s2) * uu[i];
        }
    }

    // ---- reflected row offsets (reflect mode, edge excluded) ----
    int yoff[9];
    #pragma unroll
    for (int i = 0; i < 9; ++i) {
        int yy = py + i - 4;
        yy = (yy < 0) ? -yy : yy;
        yy = (yy > HH-1) ? (2*(HH-1) - yy) : yy;
        yoff[i] = yy << 8;                            // * WW
    }

    // Column base: interior lanes load cols [px0-4, px0+7]; edge lanes load a
    // clamped aligned window that CONTAINS all reflected source columns.
    const int bcol = (px0 == 0) ? 0 : ((px0 == 252) ? 244 : px0 - 4);
    const bool edgeL = (px0 == 0);
    const bool edgeR = (px0 == 252);

    const float* xb = x + (size_t)(b * CC + c) * HW + bcol;

    float a0 = 0.f, a1 = 0.f, a2 = 0.f, a3 = 0.f;
    #pragma unroll
    for (int a = 0; a < 9; ++a) {
        const float* rp = xb + yoff[a];
        const float4 q0 = *reinterpret_cast<const float4*>(rp);
        const float4 q1 = *reinterpret_cast<const float4*>(rp + 4);
        const float4 q2 = *reinterpret_cast<const float4*>(rp + 8);
        float qv[12] = {q0.x,q0.y,q0.z,q0.w,
                        q1.x,q1.y,q1.z,q1.w,
                        q2.x,q2.y,q2.z,q2.w};

        if (edgeL) {
            // needed col m-4 for m=0..11, reflected: perm = [4,3,2,1,0,1,2,3,4,5,6,7]
            const float s0=qv[0],s1=qv[1],s2=qv[2],s3=qv[3],
                        s4=qv[4],s5=qv[5],s6=qv[6],s7=qv[7];
            qv[0]=s4; qv[1]=s3; qv[2]=s2;  qv[3]=s1;  qv[4]=s0; qv[5]=s1;
            qv[6]=s2; qv[7]=s3; qv[8]=s4;  qv[9]=s5;  qv[10]=s6; qv[11]=s7;
        } else if (edgeR) {
            // needed cols 248..255,254,253,252,251; base 244: perm = [4..11,10,9,8,7]
            const float s4=qv[4],s5=qv[5],s6=qv[6],s7=qv[7],
                        s8=qv[8],s9=qv[9],s10=qv[10],s11=qv[11];
            qv[0]=s4; qv[1]=s5; qv[2]=s6;  qv[3]=s7;  qv[4]=s8;  qv[5]=s9;
            qv[6]=s10; qv[7]=s11; qv[8]=s10; qv[9]=s9; qv[10]=s8; qv[11]=s7;
        }

        const int dy = a - 4;
        #pragma unroll
        for (int i = 0; i < 9; ++i) {
            const int dx = i - 4;
            const int wi = CMAP[dy*dy + dx*dx];       // compile-time constant
            a0 += w[0][wi] * qv[i + 0];
            a1 += w[1][wi] * qv[i + 1];
            a2 += w[2][wi] * qv[i + 2];
            a3 += w[3][wi] * qv[i + 3];
        }
    }

    float* ob = out + (size_t)(b * CC + c) * HW + p0;
    *reinterpret_cast<float4*>(ob) = make_float4(a0, a1, a2, a3);
}

extern "C" void kernel_launch(void* const* d_in, const int* in_sizes, int n_in,
                              void* d_out, int out_size, void* d_ws, size_t ws_size,
                              hipStream_t stream) {
    const float* x   = (const float*)d_in[0];   // [4,3,256,256] f32
    const float* foa = (const float*)d_in[1];   // [4,2] f32
    float* out = (float*)d_out;                 // [4,3,256,256] f32

    adaptive_log_fused<<<dim3((HW/4) / 256, 4 * CC), dim3(256), 0, stream>>>(x, foa, out);
}